// Round 18
// baseline (227.884 us; speedup 1.0000x reference)
//
#include <hip/hip_runtime.h>
#include <stdint.h>

#define BTOK 32768
#define DIN 256
#define DHID 512
#define DOUT 256
#define NEXP 16
#define BM 128
#define CH 32
#define NCH 16
#define SLOTS 96

typedef __attribute__((ext_vector_type(8))) short bf16x8;
typedef __attribute__((ext_vector_type(16))) float f32x16;

__device__ __forceinline__ unsigned short f2bf(float f){
  unsigned u = __builtin_bit_cast(unsigned, f);
  u = u + 0x7FFFu + ((u >> 16) & 1u);      // RNE, finite inputs only
  return (unsigned short)(u >> 16);
}
__device__ __forceinline__ float bf2f(unsigned short h){
  return __builtin_bit_cast(float, (unsigned)h << 16);
}
__device__ __forceinline__ void gload16(const void* g, void* l){
  __builtin_amdgcn_global_load_lds((const __attribute__((address_space(1))) unsigned int*)g,
                                   (__attribute__((address_space(3))) unsigned int*)l, 16, 0, 0);
}

// ---------------- W1 transpose + cvt: src[e][256 i][512 h] -> dst[e][512 h][256 i]
__global__ __launch_bounds__(256) void transpose_cvt(const float* __restrict__ src,
                                                     unsigned short* __restrict__ dst,
                                                     int R, int C){
  __shared__ float t[32][33];
  int e = blockIdx.z, r0 = blockIdx.y * 32, c0 = blockIdx.x * 32;
  int lx = threadIdx.x & 31, ly = threadIdx.x >> 5;
  const float* s = src + (size_t)e * R * C;
  unsigned short* d = dst + (size_t)e * R * C;
#pragma unroll
  for (int i = 0; i < 4; i++){ int r = ly + i * 8; t[r][lx] = s[(size_t)(r0 + r) * C + c0 + lx]; }
  __syncthreads();
#pragma unroll
  for (int i = 0; i < 4; i++){ int r = ly + i * 8; d[(size_t)(c0 + r) * R + r0 + lx] = f2bf(t[lx][r]); }
}

// ---------------- W2 transpose + cvt into chunk-major: src[e][512 h][256 o] -> dst[e][16][256 o][32 h]
__global__ __launch_bounds__(256) void transpose_cvt_w2(const float* __restrict__ src,
                                                        unsigned short* __restrict__ dst){
  __shared__ float t[32][33];
  int e = blockIdx.z, r0 = blockIdx.y * 32, c0 = blockIdx.x * 32;   // r0 over h, c0 over o
  int lx = threadIdx.x & 31, ly = threadIdx.x >> 5;
  const float* s = src + (size_t)e * DHID * DOUT;
  unsigned short* d = dst + (size_t)e * DHID * DOUT + (r0 >> 5) * (DOUT * CH);
#pragma unroll
  for (int i = 0; i < 4; i++){ int r = ly + i * 8; t[r][lx] = s[(size_t)(r0 + r) * DOUT + c0 + lx]; }
  __syncthreads();
#pragma unroll
  for (int i = 0; i < 4; i++){ int rr = ly + i * 8; d[(size_t)(c0 + rr) * CH + lx] = f2bf(t[lx][rr]); }
}

// ---------------- gating: 512 blocks x 64 tokens; LDS-aggregated histogram
__global__ __launch_bounds__(256) void gating_kernel(const float* __restrict__ x,
                                                     const float* __restrict__ Wg,
                                                     const float* __restrict__ bg,
                                                     unsigned short* __restrict__ x_bf,
                                                     int* __restrict__ top_idx,
                                                     float* __restrict__ top_w,
                                                     int* __restrict__ counts){
  __shared__ float WgT[16][256];
  __shared__ int hist[16];
  int tid = threadIdx.x;
#pragma unroll
  for (int j = 0; j < 4; j++){
    float4 wv = *(const float4*)(Wg + tid * 16 + j * 4);
    WgT[j * 4 + 0][tid] = wv.x; WgT[j * 4 + 1][tid] = wv.y;
    WgT[j * 4 + 2][tid] = wv.z; WgT[j * 4 + 3][tid] = wv.w;
  }
  if (tid < 16) hist[tid] = 0;
  __syncthreads();
  int wid = tid >> 6, lane = tid & 63;

  for (int t = 0; t < 16; t++){
    int tok = blockIdx.x * 64 + wid * 16 + t;
    const float4 xv = *(const float4*)(x + (size_t)tok * DIN + lane * 4);
    ushort4 xb; xb.x = f2bf(xv.x); xb.y = f2bf(xv.y); xb.z = f2bf(xv.z); xb.w = f2bf(xv.w);
    *(ushort4*)(x_bf + (size_t)tok * DIN + lane * 4) = xb;
    float logit[16];
#pragma unroll
    for (int e = 0; e < 16; e++){
      const float4 wv = *(const float4*)(&WgT[e][lane * 4]);
      float v = xv.x * wv.x + xv.y * wv.y + xv.z * wv.z + xv.w * wv.w;
#pragma unroll
      for (int off = 32; off; off >>= 1) v += __shfl_xor(v, off, 64);
      logit[e] = v + bg[e];
    }
    if (lane == 0){
      int i1 = 0; float v1 = logit[0];
#pragma unroll
      for (int e = 1; e < 16; e++) if (logit[e] > v1){ v1 = logit[e]; i1 = e; }
      int i2 = -1; float v2 = -3.4e38f;
#pragma unroll
      for (int e = 0; e < 16; e++) if (e != i1 && logit[e] > v2){ v2 = logit[e]; i2 = e; }
      float tt = expf(v2 - v1);
      float w1 = 1.0f / (1.0f + tt);
      float w2 = tt / (1.0f + tt);
      top_idx[tok * 2] = i1; top_idx[tok * 2 + 1] = i2;
      top_w[tok * 2] = w1;  top_w[tok * 2 + 1] = w2;
      atomicAdd(&hist[i1], 1); atomicAdd(&hist[i2], 1);
    }
  }
  __syncthreads();
  if (tid < 16) atomicAdd(&counts[tid], hist[tid]);
}

// ---------------- prefix sum + XCD unit lists + steal cursors (one wave)
__global__ void prefix_kernel(const int* __restrict__ counts, int* __restrict__ offsets,
                              int* __restrict__ cursor, int* __restrict__ bm_e,
                              int* __restrict__ bm_start, int* __restrict__ bm_end,
                              int* __restrict__ xcd_cnt, int* __restrict__ xcd_cur){
  int lane = threadIdx.x & 63;
  int c = (lane < 16) ? counts[lane] : 0;
  int s = c;
#pragma unroll
  for (int off = 1; off < 16; off <<= 1){ int o = __shfl_up(s, off, 64); if (lane >= off) s += o; }
  int start = s - c;
  if (lane < 16){ offsets[lane] = start; cursor[lane] = start; }
  int nb = (c + BM - 1) >> 7;
  int nb_partner = __shfl(nb, lane ^ 8, 64);
  if (lane < 8){
    int filled = nb + nb_partner;
    if (filled > SLOTS) filled = SLOTS;
    xcd_cnt[lane] = filled;
    xcd_cur[lane] = 0;
  }
  if (lane < 16){
    int sbase = (lane < 8) ? 0 : nb_partner;
    int xcd = lane & 7;
    for (int b = 0; b < nb; b++){
      int idx = xcd * SLOTS + sbase + b;
      if (sbase + b < SLOTS){
        bm_e[idx] = lane; bm_start[idx] = start + b * BM; bm_end[idx] = start + c;
      }
    }
  }
}

// ---------------- scatter: block-aggregated chunk reservation, LDS ranks
// pair_tok packs token | (k << 16) so the gemm can write token-major ypair.
__global__ __launch_bounds__(256) void scatter_kernel(const int* __restrict__ top_idx,
                                                      const float* __restrict__ top_w,
                                                      int* __restrict__ cursor,
                                                      int* __restrict__ pair_tok,
                                                      float* __restrict__ pair_w){
  __shared__ int hist[16], base[16], rank[16];
  int tid = threadIdx.x;
  if (tid < 16){ hist[tid] = 0; rank[tid] = 0; }
  __syncthreads();
  int t = blockIdx.x * 256 + tid;
  int e0 = top_idx[t * 2], e1 = top_idx[t * 2 + 1];
  float w0 = top_w[t * 2], w1 = top_w[t * 2 + 1];
  atomicAdd(&hist[e0], 1); atomicAdd(&hist[e1], 1);
  __syncthreads();
  if (tid < 16) base[tid] = atomicAdd(&cursor[tid], hist[tid]);
  __syncthreads();
  int r0 = atomicAdd(&rank[e0], 1);
  int p0 = base[e0] + r0;
  pair_tok[p0] = t; pair_w[p0] = w0;
  int r1 = atomicAdd(&rank[e1], 1);
  int p1 = base[e1] + r1;
  pair_tok[p1] = t | (1 << 16); pair_w[p1] = w1;
}

// ---------------- fused 2-layer expert MLP v18 (= v17 with the STAGE volume
// bug fixed: 16KB tiles need 4x256x16B iterations, not 8). 4 waves/block,
// CH=32/NCH=16, 74KB LDS -> TWO independent blocks/CU; persistent stealing.
__global__ __launch_bounds__(256, 2) void moe_gemm_kernel(
    const unsigned short* __restrict__ x_bf,   // [B][256]
    const unsigned short* __restrict__ W1t,    // [E][512 h][256 i]
    const unsigned short* __restrict__ W2c,    // [E][16 c][256 o][32 h]
    const float* __restrict__ b1,              // [E][512]
    const float* __restrict__ b2,              // [E][256]
    const int* __restrict__ pair_tok, const float* __restrict__ pair_w,
    const int* __restrict__ bm_e, const int* __restrict__ bm_start,
    const int* __restrict__ bm_end,
    int* __restrict__ xcd_cur, const int* __restrict__ xcd_cnt,
    unsigned short* __restrict__ ypair){       // [B*2][256] bf16, token-major
  int xcd = blockIdx.x & 7;

  __shared__ unsigned short w1s[2][CH * 256];   // 2x16KB [32 hid][256 k], 512B rows, ^(hid&15)<<4
  __shared__ unsigned short w2s[2][256 * CH];   // 2x16KB [256 o][32 k], 128B row-pairs, ^(pair&7)<<4
  __shared__ unsigned short hs[BM * CH];        // 8KB [128 tok][32 h], 128B row-pairs, ^(pair&7)<<4
  __shared__ float b1s[DHID];                   // 2KB
  __shared__ int s_u;

  int tid = threadIdx.x, wid = tid >> 6, lane = tid & 63;
  int l31 = lane & 31, l5 = lane >> 5;
  int mg = wid;                              // wave owns tokens mg*32..+31
  char* hsb = (char*)hs;

  int hid = l31;                             // chunk-local hid row (0..31)
  int swzA = (hid & 15) << 4;
  const f32x16 fzero = {0.f,0.f,0.f,0.f,0.f,0.f,0.f,0.f,0.f,0.f,0.f,0.f,0.f,0.f,0.f,0.f};
  int cnt = xcd_cnt[xcd];

  for (;;){
    if (tid == 0) s_u = atomicAdd(&xcd_cur[xcd], 1);
    __syncthreads();
    int u = s_u;
    if (u >= cnt) break;                     // uniform exit
    int bmi = xcd * SLOTS + u;
    int e = bm_e[bmi], rs = bm_start[bmi], re = bm_end[bmi];
    const char* gW1 = (const char*)(W1t + (size_t)e * DHID * DIN);
    const char* gW2 = (const char*)(W2c + (size_t)e * DOUT * DHID);

    // 16KB per tile = 1024 granules = 4 iterations x 256 threads x 16B
#define STAGE(c, sl) {                                                    \
    const char* s1 = gW1 + (size_t)(c) * 16384;                           \
    const char* s2 = gW2 + (size_t)(c) * 16384;                           \
    char* d1 = (char*)w1s[sl]; char* d2 = (char*)w2s[sl];                 \
    _Pragma("unroll")                                                     \
    for (int k = 0; k < 4; k++){                                          \
      int g = k * 256 + tid;                                              \
      int r_ = g >> 5;                                                    \
      int of1 = r_ * 512 + (((g & 31) ^ (r_ & 15)) * 16);                 \
      int p_ = g >> 3, q_ = (g & 7) ^ (p_ & 7);                           \
      int of2 = (p_ * 2 + (q_ >> 2)) * 64 + (q_ & 3) * 16;                \
      gload16(s1 + of1, d1 + g * 16);                                     \
      gload16(s2 + of2, d2 + g * 16);                                     \
    } }

    // ---- b1 -> LDS (once per unit)
    b1s[tid] = b1[e * DHID + tid];
    b1s[tid + 256] = b1[e * DHID + 256 + tid];

    // ---- x rows (wave's 32 tokens) -> registers: 16 k-frags (64 VGPR)
    bf16x8 xr[16];
    {
      int g0 = rs + mg * 32 + l31;
      int gc = g0 < re ? g0 : (re - 1);
      int tok = pair_tok[gc] & 0xFFFF;
      const unsigned short* xrow = x_bf + (size_t)tok * DIN + l5 * 8;
#pragma unroll
      for (int ks = 0; ks < 16; ks++) xr[ks] = *(const bf16x8*)(xrow + ks * 16);
    }

    f32x16 acc[8];
#pragma unroll
    for (int i = 0; i < 8; i++) acc[i] = fzero;

    STAGE(0, 0);
    asm volatile("s_waitcnt vmcnt(0)" ::: "memory");
    __builtin_amdgcn_sched_barrier(0);
    __builtin_amdgcn_s_barrier();
    __builtin_amdgcn_sched_barrier(0);

    for (int c = 0; c < NCH; c++){
      int sl = c & 1;
      if (c + 1 < NCH) STAGE(c + 1, sl ^ 1);   // lands during this chunk

      // ---- phase A: h-tile[32 tok of mg][32 hid], K=256, 2 dep-chains
      {
        const char* w1b = (const char*)w1s[sl];
        f32x16 h0 = fzero, h1 = fzero;
#pragma unroll
        for (int ks = 0; ks < 16; ks += 2){
          bf16x8 bA = *(const bf16x8*)(w1b + hid * 512 + ((ks * 32 + l5 * 16) ^ swzA));
          bf16x8 bB = *(const bf16x8*)(w1b + hid * 512 + (((ks + 1) * 32 + l5 * 16) ^ swzA));
          h0 = __builtin_amdgcn_mfma_f32_32x32x16_bf16(xr[ks], bA, h0, 0, 0, 0);
          h1 = __builtin_amdgcn_mfma_f32_32x32x16_bf16(xr[ks + 1], bB, h1, 0, 0, 0);
        }
        f32x16 hsum = h0 + h1;
        float b1v = b1s[c * CH + l31];
        // relu(h+b1) -> hs; C/D: col=lane&31 (hid), row=(reg&3)+8*(reg>>2)+4*(lane>>5)
#pragma unroll
        for (int r = 0; r < 16; r++){
          int tk = mg * 32 + (r & 3) + ((r >> 2) << 3) + (l5 << 2);
          float v = fmaxf(hsum[r] + b1v, 0.f);
          int adr = (tk >> 1) * 128 + ((((tk & 1) << 6) + l31 * 2) ^ (((tk >> 1) & 7) << 4));
          *(unsigned short*)(hsb + adr) = f2bf(v);
        }
      }
      asm volatile("s_waitcnt lgkmcnt(0)" ::: "memory");
      __builtin_amdgcn_sched_barrier(0);
      __builtin_amdgcn_s_barrier();
      __builtin_amdgcn_sched_barrier(0);

      // ---- phase B: y[32 tok of mg][256 out] += h @ W2c (K=32)
      {
        const char* w2b = (const char*)w2s[sl];
        int tk = mg * 32 + l31;
        int hb = (tk >> 1) * 128, hswz = ((tk >> 1) & 7) << 4, hhi = (tk & 1) << 6;
        bf16x8 ha[2];
#pragma unroll
        for (int ks = 0; ks < 2; ks++)
          ha[ks] = *(const bf16x8*)(hsb + hb + ((hhi + ks * 32 + l5 * 16) ^ hswz));
#pragma unroll
        for (int ot = 0; ot < 8; ot++){
          int n = ot * 32 + l31;
          int nb_ = (n >> 1) * 128, nswz = ((n >> 1) & 7) << 4, nhi = (n & 1) << 6;
#pragma unroll
          for (int ks = 0; ks < 2; ks++){
            bf16x8 bb = *(const bf16x8*)(w2b + nb_ + ((nhi + ks * 32 + l5 * 16) ^ nswz));
            acc[ot] = __builtin_amdgcn_mfma_f32_32x32x16_bf16(ha[ks], bb, acc[ot], 0, 0, 0);
          }
        }
      }
      if (c + 1 < NCH){
        asm volatile("s_waitcnt vmcnt(0) lgkmcnt(0)" ::: "memory");
        __builtin_amdgcn_sched_barrier(0);
        __builtin_amdgcn_s_barrier();
        __builtin_amdgcn_sched_barrier(0);
      }
    }

    // ---- epilogue: fold gate weight + b2, store token-major bf16 rows
    {
      float b2v[8];
#pragma unroll
      for (int ot = 0; ot < 8; ot++) b2v[ot] = b2[e * DOUT + ot * 32 + l31];
#pragma unroll
      for (int r = 0; r < 16; r++){
        int tl = mg * 32 + (r & 3) + ((r >> 2) << 3) + (l5 << 2);
        int gg = rs + tl;
        if (gg < re){
          int pt = pair_tok[gg];
          int yrow = (pt & 0xFFFF) * 2 + (pt >> 16);
          float w = pair_w[gg];
          unsigned short* yp = ypair + (size_t)yrow * DOUT + l31;
#pragma unroll
          for (int ot = 0; ot < 8; ot++)
            yp[ot * 32] = f2bf(w * (acc[ot][r] + b2v[ot]));
        }
      }
    }
#undef STAGE
  }
}

// ---------------- combine: out[t] = yp[2t] + yp[2t+1], fully coalesced
__global__ __launch_bounds__(256) void combine_kernel(const unsigned short* __restrict__ yp,
                                                      float* __restrict__ out){
  int idx = blockIdx.x * 256 + threadIdx.x;
  int t = idx >> 6;
  int c4 = (idx & 63) << 2;
  ushort4 a = *(const ushort4*)(yp + (size_t)(t * 2) * DOUT + c4);
  ushort4 b = *(const ushort4*)(yp + (size_t)(t * 2 + 1) * DOUT + c4);
  float4 o;
  o.x = bf2f(a.x) + bf2f(b.x);
  o.y = bf2f(a.y) + bf2f(b.y);
  o.z = bf2f(a.z) + bf2f(b.z);
  o.w = bf2f(a.w) + bf2f(b.w);
  *(float4*)(out + (size_t)t * DOUT + c4) = o;
}

extern "C" void kernel_launch(void* const* d_in, const int* in_sizes, int n_in,
                              void* d_out, int out_size, void* d_ws, size_t ws_size,
                              hipStream_t stream){
  (void)in_sizes; (void)n_in; (void)out_size; (void)ws_size;
  const float* x  = (const float*)d_in[0];
  const float* Wg = (const float*)d_in[1];
  const float* bg = (const float*)d_in[2];
  const float* W1 = (const float*)d_in[3];
  const float* b1 = (const float*)d_in[4];
  const float* W2 = (const float*)d_in[5];
  const float* b2 = (const float*)d_in[6];
  float* out = (float*)d_out;
  char* ws = (char*)d_ws;

  unsigned short* x_bf  = (unsigned short*)(ws);                 // 16,777,216
  unsigned short* W1t   = (unsigned short*)(ws + 16777216);      //  4,194,304
  unsigned short* W2ck  = (unsigned short*)(ws + 20971520);      //  4,194,304
  unsigned short* ypair = (unsigned short*)(ws + 25165824);      // 33,554,432
  int*   top_idx  = (int*)  (ws + 58720256);
  float* top_w    = (float*)(ws + 58982400);
  int*   pair_tok = (int*)  (ws + 59244544);
  float* pair_w   = (float*)(ws + 59506688);
  int*   counts   = (int*)  (ws + 60030976);
  int*   offsets  = (int*)  (ws + 60031040);
  int*   cursor   = (int*)  (ws + 60031104);
  int*   bm_e     = (int*)  (ws + 60031232);   // 768 ints
  int*   bm_start = (int*)  (ws + 60036608);   // 768 ints
  int*   bm_end   = (int*)  (ws + 60041984);   // 768 ints
  int*   xcd_cnt  = (int*)  (ws + 60045184);   // 8 ints
  int*   xcd_cur  = (int*)  (ws + 60045248);   // 8 ints

  hipMemsetAsync(counts, 0, 64, stream);
  transpose_cvt<<<dim3(16, 8, 16), 256, 0, stream>>>(W1, W1t, 256, 512);
  transpose_cvt_w2<<<dim3(8, 16, 16), 256, 0, stream>>>(W2, W2ck);
  gating_kernel<<<512, 256, 0, stream>>>(x, Wg, bg, x_bf, top_idx, top_w, counts);
  prefix_kernel<<<1, 64, 0, stream>>>(counts, offsets, cursor, bm_e, bm_start, bm_end,
                                      xcd_cnt, xcd_cur);
  scatter_kernel<<<128, 256, 0, stream>>>(top_idx, top_w, cursor, pair_tok, pair_w);
  moe_gemm_kernel<<<512, 256, 0, stream>>>(x_bf, W1t, W2ck, b1, b2, pair_tok, pair_w,
                                           bm_e, bm_start, bm_end, xcd_cur, xcd_cnt, ypair);
  combine_kernel<<<8192, 256, 0, stream>>>(ypair, out);
}

// Round 19
// 153.679 us; speedup vs baseline: 1.4829x; 1.4829x over previous
//
#include <hip/hip_runtime.h>
#include <stdint.h>

#define BTOK 32768
#define DIN 256
#define DHID 512
#define DOUT 256
#define NEXP 16
#define BM 128
#define CH 64
#define NCH 8

typedef __attribute__((ext_vector_type(8))) short bf16x8;
typedef __attribute__((ext_vector_type(16))) float f32x16;

__device__ __forceinline__ unsigned short f2bf(float f){
  unsigned u = __builtin_bit_cast(unsigned, f);
  u = u + 0x7FFFu + ((u >> 16) & 1u);      // RNE, finite inputs only
  return (unsigned short)(u >> 16);
}
__device__ __forceinline__ float bf2f(unsigned short h){
  return __builtin_bit_cast(float, (unsigned)h << 16);
}
__device__ __forceinline__ void gload16(const void* g, void* l){
  __builtin_amdgcn_global_load_lds((const __attribute__((address_space(1))) unsigned int*)g,
                                   (__attribute__((address_space(3))) unsigned int*)l, 16, 0, 0);
}

// ---------------- fused weight transposes (one launch, 4096 blocks, 4.2KB LDS)
// bid < 2048 : W1 [e][256 i][512 h] -> W1t [e][512 h][256 i]
// bid >= 2048: W2 [e][512 h][256 o] -> W2c [e][8 c][256 o][64 h] (chunk-major)
__global__ __launch_bounds__(256) void transpose_fused(const float* __restrict__ W1,
                                                       const float* __restrict__ W2,
                                                       unsigned short* __restrict__ W1t,
                                                       unsigned short* __restrict__ W2c){
  __shared__ float t[32][33];
  int bid = blockIdx.x, tid = threadIdx.x;
  int lx = tid & 31, ly = tid >> 5;
  if (bid < 2048){
    int bx = bid & 15, by = (bid >> 4) & 7, bz = bid >> 7;
    int r0 = by * 32, c0 = bx * 32;            // r0 over i (256), c0 over h (512)
    const float* s = W1 + (size_t)bz * 256 * 512;
    unsigned short* d = W1t + (size_t)bz * 256 * 512;
#pragma unroll
    for (int i = 0; i < 4; i++){ int r = ly + i * 8; t[r][lx] = s[(size_t)(r0 + r) * 512 + c0 + lx]; }
    __syncthreads();
#pragma unroll
    for (int i = 0; i < 4; i++){ int r = ly + i * 8; d[(size_t)(c0 + r) * 256 + r0 + lx] = f2bf(t[lx][r]); }
  } else {
    int b2 = bid - 2048;
    int bx = b2 & 7, by = (b2 >> 3) & 15, bz = b2 >> 7;
    int r0 = by * 32, c0 = bx * 32;            // r0 over h (512), c0 over o (256)
    const float* s = W2 + (size_t)bz * DHID * DOUT;
    unsigned short* d = W2c + (size_t)bz * DHID * DOUT + (r0 >> 6) * (DOUT * CH) + (r0 & 32);
#pragma unroll
    for (int i = 0; i < 4; i++){ int r = ly + i * 8; t[r][lx] = s[(size_t)(r0 + r) * DOUT + c0 + lx]; }
    __syncthreads();
#pragma unroll
    for (int i = 0; i < 4; i++){ int rr = ly + i * 8; d[(size_t)(c0 + rr) * CH + lx] = f2bf(t[lx][rr]); }
  }
}

// ---------------- gating: 512 blocks x 64 tokens; LDS-aggregated histogram
__global__ __launch_bounds__(256) void gating_kernel(const float* __restrict__ x,
                                                     const float* __restrict__ Wg,
                                                     const float* __restrict__ bg,
                                                     unsigned short* __restrict__ x_bf,
                                                     int* __restrict__ top_idx,
                                                     float* __restrict__ top_w,
                                                     int* __restrict__ counts){
  __shared__ float WgT[16][256];
  __shared__ int hist[16];
  int tid = threadIdx.x;
#pragma unroll
  for (int j = 0; j < 4; j++){
    float4 wv = *(const float4*)(Wg + tid * 16 + j * 4);
    WgT[j * 4 + 0][tid] = wv.x; WgT[j * 4 + 1][tid] = wv.y;
    WgT[j * 4 + 2][tid] = wv.z; WgT[j * 4 + 3][tid] = wv.w;
  }
  if (tid < 16) hist[tid] = 0;
  __syncthreads();
  int wid = tid >> 6, lane = tid & 63;

  for (int t = 0; t < 16; t++){
    int tok = blockIdx.x * 64 + wid * 16 + t;
    const float4 xv = *(const float4*)(x + (size_t)tok * DIN + lane * 4);
    ushort4 xb; xb.x = f2bf(xv.x); xb.y = f2bf(xv.y); xb.z = f2bf(xv.z); xb.w = f2bf(xv.w);
    *(ushort4*)(x_bf + (size_t)tok * DIN + lane * 4) = xb;
    float logit[16];
#pragma unroll
    for (int e = 0; e < 16; e++){
      const float4 wv = *(const float4*)(&WgT[e][lane * 4]);
      float v = xv.x * wv.x + xv.y * wv.y + xv.z * wv.z + xv.w * wv.w;
#pragma unroll
      for (int off = 32; off; off >>= 1) v += __shfl_xor(v, off, 64);
      logit[e] = v + bg[e];
    }
    if (lane == 0){
      int i1 = 0; float v1 = logit[0];
#pragma unroll
      for (int e = 1; e < 16; e++) if (logit[e] > v1){ v1 = logit[e]; i1 = e; }
      int i2 = -1; float v2 = -3.4e38f;
#pragma unroll
      for (int e = 0; e < 16; e++) if (e != i1 && logit[e] > v2){ v2 = logit[e]; i2 = e; }
      float tt = expf(v2 - v1);
      float w1 = 1.0f / (1.0f + tt);
      float w2 = tt / (1.0f + tt);
      top_idx[tok * 2] = i1; top_idx[tok * 2 + 1] = i2;
      top_w[tok * 2] = w1;  top_w[tok * 2 + 1] = w2;
      atomicAdd(&hist[i1], 1); atomicAdd(&hist[i2], 1);
    }
  }
  __syncthreads();
  if (tid < 16) atomicAdd(&counts[tid], hist[tid]);
}

// ---------------- scatter: local scan of counts (no prefix kernel),
// block-aggregated chunk reservation. pair_tok packs token | (k<<16).
__global__ __launch_bounds__(256) void scatter_kernel(const int* __restrict__ top_idx,
                                                      const float* __restrict__ top_w,
                                                      const int* __restrict__ counts,
                                                      int* __restrict__ cursor,
                                                      int* __restrict__ pair_tok,
                                                      float* __restrict__ pair_w){
  __shared__ int hist[16], base[16], rank[16], offs[16];
  int tid = threadIdx.x;
  if (tid < 16){ hist[tid] = 0; rank[tid] = 0; }
  __syncthreads();
  int t = blockIdx.x * 256 + tid;
  int e0 = top_idx[t * 2], e1 = top_idx[t * 2 + 1];
  float w0 = top_w[t * 2], w1 = top_w[t * 2 + 1];
  atomicAdd(&hist[e0], 1); atomicAdd(&hist[e1], 1);
  if (tid < 64){                      // wave 0: exclusive scan of counts
    int lane = tid;
    int c = (lane < 16) ? counts[lane] : 0;
    int s = c;
#pragma unroll
    for (int off = 1; off < 16; off <<= 1){ int o = __shfl_up(s, off, 64); if (lane >= off) s += o; }
    if (lane < 16) offs[lane] = s - c;
  }
  __syncthreads();
  if (tid < 16) base[tid] = offs[tid] + atomicAdd(&cursor[tid], hist[tid]);
  __syncthreads();
  int r0 = atomicAdd(&rank[e0], 1);
  int p0 = base[e0] + r0;
  pair_tok[p0] = t; pair_w[p0] = w0;
  int r1 = atomicAdd(&rank[e1], 1);
  int p1 = base[e1] + r1;
  pair_tok[p1] = t | (1 << 16); pair_w[p1] = w1;
}

// ---------------- fused 2-layer expert MLP (R16 internals verbatim: 32x32
// MFMA, 16-granule XOR swizzles, dbuf global_load_lds staging, raw barriers,
// persistent per-XCD stealing). Unit mapping derived in-kernel from counts.
__global__ __launch_bounds__(512, 1) void moe_gemm_kernel(
    const unsigned short* __restrict__ x_bf,   // [B][256]
    const unsigned short* __restrict__ W1t,    // [E][512 h][256 i]
    const unsigned short* __restrict__ W2c,    // [E][8 c][256 o][64 h]
    const float* __restrict__ b1,              // [E][512]
    const float* __restrict__ b2,              // [E][256]
    const int* __restrict__ pair_tok, const float* __restrict__ pair_w,
    const int* __restrict__ counts,
    int* __restrict__ xcd_cur,
    unsigned short* __restrict__ ypair){       // [B*2][256] bf16, token-major
  int xcd = blockIdx.x & 7;

  __shared__ unsigned short w1s[2][CH * 256];   // 2x32KB [64 hid][256 k], 512B rows, ^(hid&15)<<4
  __shared__ unsigned short w2s[2][256 * CH];   // 2x32KB [256 o][64 k], 256B row-pairs, ^(pair&15)<<4
  __shared__ unsigned short hs[BM * CH];        // 16KB [128 tok][64 h], 256B row-pairs, ^(pair&15)<<4
  __shared__ int s_map[6];
  __shared__ int s_u;

  int tid = threadIdx.x, wid = tid >> 6, lane = tid & 63;
  int l31 = lane & 31, l5 = lane >> 5;
  int mg = wid >> 1, hg = wid & 1;
  char* hsb = (char*)hs;

  // ---- derive this XCD's (expert, start, count) mapping from counts
  if (tid < 64){
    int c = (lane < 16) ? counts[lane] : 0;
    int s = c;
#pragma unroll
    for (int off = 1; off < 16; off <<= 1){ int o = __shfl_up(s, off, 64); if (lane >= off) s += o; }
    int start = s - c;
    int c0 = __shfl(c, xcd, 64),     st0 = __shfl(start, xcd, 64);
    int c1 = __shfl(c, xcd + 8, 64), st1 = __shfl(start, xcd + 8, 64);
    if (lane == 0){
      int nb0 = (c0 + BM - 1) >> 7, nb1 = (c1 + BM - 1) >> 7;
      s_map[0] = c0; s_map[1] = st0; s_map[2] = c1; s_map[3] = st1;
      s_map[4] = nb0; s_map[5] = nb0 + nb1;
    }
  }
  __syncthreads();
  int mc0 = s_map[0], mst0 = s_map[1], mc1 = s_map[2], mst1 = s_map[3];
  int nb0 = s_map[4], cnt = s_map[5];

  // pre-swizzled staging source offsets (linear LDS dest; +k*8192 preserves XOR bits)
  int o1, o2;
  { int r = tid >> 5; o1 = r * 512 + (((tid & 31) ^ (r & 15)) * 16); }
  { int p = tid >> 4; int q = (tid & 15) ^ (p & 15);
    o2 = (p * 2 + (q >> 3)) * 128 + (q & 7) * 16; }

  int hid = hg * 32 + l31;                 // chunk-local hid row this wave reads/writes
  int swzA = (hid & 15) << 4;
  const f32x16 fzero = {0.f,0.f,0.f,0.f,0.f,0.f,0.f,0.f,0.f,0.f,0.f,0.f,0.f,0.f,0.f,0.f};

  for (;;){
    if (tid == 0) s_u = atomicAdd(&xcd_cur[xcd], 1);
    __syncthreads();
    int u = s_u;
    if (u >= cnt) break;                   // uniform exit
    int e, rs, re;
    if (u < nb0){ e = xcd;     rs = mst0 + u * BM;         re = mst0 + mc0; }
    else        { e = xcd + 8; rs = mst1 + (u - nb0) * BM; re = mst1 + mc1; }
    const char* gW1 = (const char*)(W1t + (size_t)e * DHID * DIN);
    const char* gW2 = (const char*)(W2c + (size_t)e * DOUT * DHID);

#define STAGE(c, sl) {                                                    \
    const char* s1 = gW1 + (size_t)(c) * 32768;                           \
    const char* s2 = gW2 + (size_t)(c) * 32768;                           \
    char* d1 = (char*)w1s[sl]; char* d2 = (char*)w2s[sl];                 \
    _Pragma("unroll")                                                     \
    for (int k = 0; k < 4; k++){                                          \
      gload16(s1 + o1 + k * 8192, d1 + tid * 16 + k * 8192);              \
      gload16(s2 + o2 + k * 8192, d2 + tid * 16 + k * 8192);              \
    } }

    // ---- x rows (wave's 32 tokens) -> registers: 16 k-frags (64 VGPR)
    bf16x8 xr[16];
    {
      int g0 = rs + mg * 32 + l31;
      int gc = g0 < re ? g0 : (re - 1);
      int tok = pair_tok[gc] & 0xFFFF;
      const unsigned short* xrow = x_bf + (size_t)tok * DIN + l5 * 8;
#pragma unroll
      for (int ks = 0; ks < 16; ks++) xr[ks] = *(const bf16x8*)(xrow + ks * 16);
    }

    f32x16 acc[4];
    acc[0] = fzero; acc[1] = fzero; acc[2] = fzero; acc[3] = fzero;

    STAGE(0, 0);
    asm volatile("s_waitcnt vmcnt(0)" ::: "memory");
    __builtin_amdgcn_sched_barrier(0);
    __builtin_amdgcn_s_barrier();
    __builtin_amdgcn_sched_barrier(0);

    for (int c = 0; c < NCH; c++){
      int sl = c & 1;
      if (c + 1 < NCH) STAGE(c + 1, sl ^ 1);     // lands during this chunk

      float b1v = b1[e * DHID + c * CH + hid];

      // ---- phase A: h-tile[32 tok of mg][32 hid of hg], K=256, 2 dep-chains
      {
        const char* w1b = (const char*)w1s[sl];
        f32x16 h0 = fzero, h1 = fzero;
#pragma unroll
        for (int ks = 0; ks < 16; ks += 2){
          bf16x8 bA = *(const bf16x8*)(w1b + hid * 512 + ((ks * 32 + l5 * 16) ^ swzA));
          bf16x8 bB = *(const bf16x8*)(w1b + hid * 512 + (((ks + 1) * 32 + l5 * 16) ^ swzA));
          h0 = __builtin_amdgcn_mfma_f32_32x32x16_bf16(xr[ks], bA, h0, 0, 0, 0);
          h1 = __builtin_amdgcn_mfma_f32_32x32x16_bf16(xr[ks + 1], bB, h1, 0, 0, 0);
        }
        f32x16 hsum = h0 + h1;
        // relu(h+b1) -> hs; C/D: col=lane&31, row=(reg&3)+8*(reg>>2)+4*(lane>>5)
        int h2 = hg * 64 + l31 * 2;
#pragma unroll
        for (int r = 0; r < 16; r++){
          int tk = mg * 32 + (r & 3) + ((r >> 2) << 3) + (l5 << 2);
          float v = fmaxf(hsum[r] + b1v, 0.f);
          int adr = (tk >> 1) * 256 + ((((tk & 1) << 7) + h2) ^ (((tk >> 1) & 15) << 4));
          *(unsigned short*)(hsb + adr) = f2bf(v);
        }
      }
      asm volatile("s_waitcnt lgkmcnt(0)" ::: "memory");
      __builtin_amdgcn_sched_barrier(0);
      __builtin_amdgcn_s_barrier();
      __builtin_amdgcn_sched_barrier(0);

      // ---- phase B: y[32 tok of mg][128 out of hg] += h @ W2c (K=64)
      {
        const char* w2b = (const char*)w2s[sl];
        int tk = mg * 32 + l31;
        int hswz = ((tk >> 1) & 15) << 4;
        int hbase = (tk >> 1) * 256;
        int hhi = (tk & 1) << 7;
#pragma unroll
        for (int ks = 0; ks < 4; ks++){
          bf16x8 ha = *(const bf16x8*)(hsb + hbase + ((hhi + ks * 32 + l5 * 16) ^ hswz));
#pragma unroll
          for (int ot = 0; ot < 4; ot++){
            int n = hg * 128 + ot * 32 + l31;
            int adr = (n >> 1) * 256 + ((((n & 1) << 7) + ks * 32 + l5 * 16) ^ (((n >> 1) & 15) << 4));
            bf16x8 bb = *(const bf16x8*)(w2b + adr);
            acc[ot] = __builtin_amdgcn_mfma_f32_32x32x16_bf16(ha, bb, acc[ot], 0, 0, 0);
          }
        }
      }
      if (c + 1 < NCH){
        asm volatile("s_waitcnt vmcnt(0) lgkmcnt(0)" ::: "memory");
        __builtin_amdgcn_sched_barrier(0);
        __builtin_amdgcn_s_barrier();
        __builtin_amdgcn_sched_barrier(0);
      }
    }

    // ---- epilogue: fold gate weight + b2, store token-major bf16 rows
    {
      float b2v[4];
#pragma unroll
      for (int ot = 0; ot < 4; ot++) b2v[ot] = b2[e * DOUT + hg * 128 + ot * 32 + l31];
#pragma unroll
      for (int r = 0; r < 16; r++){
        int tl = mg * 32 + (r & 3) + ((r >> 2) << 3) + (l5 << 2);
        int gg = rs + tl;
        if (gg < re){
          int pt = pair_tok[gg];
          int yrow = (pt & 0xFFFF) * 2 + (pt >> 16);
          float w = pair_w[gg];
          unsigned short* yp = ypair + (size_t)yrow * DOUT + hg * 128 + l31;
#pragma unroll
          for (int ot = 0; ot < 4; ot++)
            yp[ot * 32] = f2bf(w * (acc[ot][r] + b2v[ot]));
        }
      }
    }
#undef STAGE
  }
}

// ---------------- combine: out[t] = yp[2t] + yp[2t+1], fully coalesced
__global__ __launch_bounds__(256) void combine_kernel(const unsigned short* __restrict__ yp,
                                                      float* __restrict__ out){
  int idx = blockIdx.x * 256 + threadIdx.x;
  int t = idx >> 6;
  int c4 = (idx & 63) << 2;
  ushort4 a = *(const ushort4*)(yp + (size_t)(t * 2) * DOUT + c4);
  ushort4 b = *(const ushort4*)(yp + (size_t)(t * 2 + 1) * DOUT + c4);
  float4 o;
  o.x = bf2f(a.x) + bf2f(b.x);
  o.y = bf2f(a.y) + bf2f(b.y);
  o.z = bf2f(a.z) + bf2f(b.z);
  o.w = bf2f(a.w) + bf2f(b.w);
  *(float4*)(out + (size_t)t * DOUT + c4) = o;
}

extern "C" void kernel_launch(void* const* d_in, const int* in_sizes, int n_in,
                              void* d_out, int out_size, void* d_ws, size_t ws_size,
                              hipStream_t stream){
  (void)in_sizes; (void)n_in; (void)out_size; (void)ws_size;
  const float* x  = (const float*)d_in[0];
  const float* Wg = (const float*)d_in[1];
  const float* bg = (const float*)d_in[2];
  const float* W1 = (const float*)d_in[3];
  const float* b1 = (const float*)d_in[4];
  const float* W2 = (const float*)d_in[5];
  const float* b2 = (const float*)d_in[6];
  float* out = (float*)d_out;
  char* ws = (char*)d_ws;

  unsigned short* x_bf  = (unsigned short*)(ws);                 // 16,777,216
  unsigned short* W1t   = (unsigned short*)(ws + 16777216);      //  4,194,304
  unsigned short* W2ck  = (unsigned short*)(ws + 20971520);      //  4,194,304
  unsigned short* ypair = (unsigned short*)(ws + 25165824);      // 33,554,432
  int*   top_idx  = (int*)  (ws + 58720256);
  float* top_w    = (float*)(ws + 58982400);
  int*   pair_tok = (int*)  (ws + 59244544);
  float* pair_w   = (float*)(ws + 59506688);
  int*   counts   = (int*)  (ws + 60030976);   // 16 ints
  int*   cursor   = (int*)  (ws + 60031040);   // 16 ints
  int*   xcd_cur  = (int*)  (ws + 60031104);   // 8 ints

  hipMemsetAsync(counts, 0, 192, stream);      // counts + cursor + xcd_cur
  transpose_fused<<<4096, 256, 0, stream>>>(W1, W2, W1t, W2ck);
  gating_kernel<<<512, 256, 0, stream>>>(x, Wg, bg, x_bf, top_idx, top_w, counts);
  scatter_kernel<<<128, 256, 0, stream>>>(top_idx, top_w, counts, cursor, pair_tok, pair_w);
  moe_gemm_kernel<<<256, 512, 0, stream>>>(x_bf, W1t, W2ck, b1, b2, pair_tok, pair_w,
                                           counts, xcd_cur, ypair);
  combine_kernel<<<8192, 256, 0, stream>>>(ypair, out);
}